// Round 8
// baseline (255.414 us; speedup 1.0000x reference)
//
#include <hip/hip_runtime.h>

// GCN: 3-layer GraphConv (norm='both') + mean over nodes.
// Round 23: R22 (217.4us best) + two staging eliminations via COALESCED
// device atomics (R18/R19 lesson: scattered atomics lose, coalesced win):
//  1) Tq deleted: tqsc flushes its contiguous LDS bins straight into
//     qtacc with skip-zero coalesced f32 atomicAdds (~2M into 200KB L2-
//     resident). Kills 12.8MB write + 12.8MB read + agg1's qt tail.
//  2) final_kernel deleted: gemm2 blocks atomicAdd their column sums
//     into cacc[F]; last block (threadfence + ticket) computes
//     out = c@W3 + b3 inline (cacc re-read via atomicAdd(p,0) to bypass
//     stale L1 across XCDs). part2 deleted.
// scanC zeroes qtacc/cacc/ticket each launch. Dispatches 8 -> 7.
#define N_NODES 50000
#define N_EDGES 800000
#define F 128
#define SCAN_NB 49      // scanC blocks / 1024-node ranges
#define CH 64           // edge chunks (4*CH = 256 blocks)
#define EPC (N_EDGES / CH)   // 12500 edges per chunk
#define HALF 25000      // node half-range (packed 8-bit hist)
#define QTR 12500       // node quarter-range (cursors / float bins)
#define BSTRIDE 17      // uint4 per LDS row (odd -> conflict-free ds_read_b128)
#define AGG_NB (N_NODES / 4)   // 12500 agg blocks (4 waves, 1 row/wave)
#define GB ((N_NODES + 63) / 64)  // 782 gemm blocks

typedef __bf16 bf16x8 __attribute__((ext_vector_type(8)));
typedef float  f32x4  __attribute__((ext_vector_type(4)));
typedef float  f32x2  __attribute__((ext_vector_type(2)));

__device__ inline unsigned short f2bf(float f) {  // RNE fp32 -> bf16 bits
    unsigned u = __float_as_uint(f);
    u += 0x7FFF + ((u >> 16) & 1);
    return (unsigned short)(u >> 16);
}
__device__ inline unsigned packbf2(float a, float b) {
    return (unsigned)f2bf(a) | ((unsigned)f2bf(b) << 16);
}

// ---- fp8 e4m3 (OCP on gfx950) helpers ----
__device__ inline void fp8x8_to_f32(uint2 u, float* f) {
    f32x2 v0 = __builtin_amdgcn_cvt_pk_f32_fp8(u.x, false);
    f32x2 v1 = __builtin_amdgcn_cvt_pk_f32_fp8(u.x, true);
    f32x2 v2 = __builtin_amdgcn_cvt_pk_f32_fp8(u.y, false);
    f32x2 v3 = __builtin_amdgcn_cvt_pk_f32_fp8(u.y, true);
    f[0] = v0.x; f[1] = v0.y; f[2] = v1.x; f[3] = v1.y;
    f[4] = v2.x; f[5] = v2.y; f[6] = v3.x; f[7] = v3.y;
}
__device__ inline unsigned f32x4_to_fp8(float a, float b, float c, float d) {
    unsigned r = __builtin_amdgcn_cvt_pk_fp8_f32(a, b, 0, false);
    r = __builtin_amdgcn_cvt_pk_fp8_f32(c, d, r, true);
    return r;
}

// ---- 8-bit chunked histograms: block = (chunk, type, half) ----
// dst-blocks additionally emit per-1024-node-range partial degree sums
// (bsump[(c*2+h)][r]) for scanC's cross-block prefix base — race-free.
__global__ __launch_bounds__(1024) void hist_kernel(const int* __restrict__ src,
                                                    const int* __restrict__ dst,
                                                    unsigned char* __restrict__ Hs8,
                                                    unsigned char* __restrict__ Hd8,
                                                    int* __restrict__ bsump) {
    __shared__ unsigned hist[HALF / 4];  // 25 KB (4x8-bit packed)
    int bx = blockIdx.x;                 // 256 blocks
    int c = bx >> 2, t = bx & 1, h = (bx >> 1) & 1;
    const int* ids = t ? dst : src;
    unsigned char* H = t ? Hd8 : Hs8;
    int base = h * HALF;
    for (int j = threadIdx.x; j < HALF / 4; j += 1024) hist[j] = 0;
    __syncthreads();
    int e0 = c * EPC;
    for (int e = e0 + threadIdx.x; e < e0 + EPC; e += 1024) {
        int id = ids[e] - base;
        if ((unsigned)id < (unsigned)HALF)
            atomicAdd(&hist[id >> 2], 1u << ((id & 3) * 8));
    }
    __syncthreads();
    unsigned* Hw = (unsigned*)(H + (size_t)c * N_NODES + base);
    for (int j = threadIdx.x; j < HALF / 4; j += 1024) Hw[j] = hist[j];
    if (t) {  // per-range degD partials for the scan base
        int w = threadIdx.x >> 6, lane = threadIdx.x & 63;
        for (int r = w; r < SCAN_NB; r += 16) {
            int gi0 = max(r * 1024, base);
            int gi1 = min(r * 1024 + 1024, base + HALF);
            int s = 0;
            for (int li = gi0 - base + lane; li < gi1 - base; li += 64)
                s += (hist[li >> 2] >> ((li & 3) * 8)) & 255;
#pragma unroll
            for (int off = 32; off; off >>= 1) s += __shfl_down(s, off);
            if (lane == 0) bsump[(c * 2 + h) * SCAN_NB + r] = s;
        }
    }
}

// ---- scanC: degrees + norms + rowst + P8 + accumulator zeroing ----
__global__ __launch_bounds__(1024) void scanC_kernel(const unsigned char* __restrict__ Hs8,
                                                     const unsigned char* __restrict__ Hd8,
                                                     const int* __restrict__ bsump,
                                                     float* __restrict__ onorm,
                                                     float* __restrict__ inorm,
                                                     int* __restrict__ rowst,
                                                     unsigned char* __restrict__ P8,
                                                     float* __restrict__ qtacc,
                                                     float* __restrict__ cacc,
                                                     int* __restrict__ ticket) {
    __shared__ int wsum[16];
    __shared__ int tot[SCAN_NB];
    int t = threadIdx.x, lane = t & 63, w = t >> 6;
    int i = blockIdx.x * 1024 + t;
    if (blockIdx.x == 0) {          // zero the atomic accumulators
        if (t < F) cacc[t] = 0.0f;
        if (t == F) *ticket = 0;
    }
    if (t < SCAN_NB) {  // per-range degD totals (128 partials each)
        int s = 0;
        for (int p = 0; p < 2 * CH; p++) s += bsump[p * SCAN_NB + t];
        tot[t] = s;
    }
    int dd = 0;
    if (i < N_NODES) {
        int ds = 0, run = 0;
        for (int c = 0; c < CH; c++) {
            size_t o = (size_t)c * N_NODES + i;
            ds += Hs8[o];
            P8[o] = (unsigned char)run;   // within-row prefix (<= deg <= 255)
            run += Hd8[o];
        }
        dd = run;
        onorm[i] = rsqrtf(fmaxf((float)ds, 1.0f));
        inorm[i] = rsqrtf(fmaxf((float)dd, 1.0f));
        qtacc[i] = 0.0f;
    }
    int v = dd, incl = v;
#pragma unroll
    for (int off = 1; off < 64; off <<= 1) {
        int u = __shfl_up(incl, off);
        if (lane >= off) incl += u;
    }
    if (lane == 63) wsum[w] = incl;
    __syncthreads();
    if (t == 0) {
        int s = 0;
        for (int r = 0; r < (int)blockIdx.x; r++) s += tot[r];
#pragma unroll
        for (int k = 0; k < 16; k++) { int x = wsum[k]; wsum[k] = s; s += x; }
    }
    __syncthreads();
    incl += wsum[w];
    if (i < N_NODES) {
        rowst[i] = incl - v;           // exclusive prefix
        if (i == N_NODES - 1) rowst[N_NODES] = incl;
    }
}

// ---- tqsc: single-sweep tq-bin + scatter + prep tail: block = (chunk, q) ----
// ONE pass over the chunk's edges; BOTH LDS images live simultaneously:
//   src in quarter q -> float-bin atomicAdd (a[], 50KB)
//   dst in quarter q -> cursor scatter (cur[], 50KB) -> esrc
// Bins flushed via skip-zero COALESCED global f32 atomics into qtacc
// (200KB, L2-resident) — no Tq staging array.
__global__ __launch_bounds__(1024) void tqsc_kernel(const int* __restrict__ src,
                                                    const int* __restrict__ dst,
                                                    const float* __restrict__ inorm,
                                                    float* __restrict__ qtacc,
                                                    const int* __restrict__ rowst,
                                                    const unsigned char* __restrict__ P8,
                                                    int* __restrict__ esrc,
                                                    const float* __restrict__ feat,
                                                    const float* __restrict__ onorm,
                                                    uint2* __restrict__ xq,
                                                    const float* __restrict__ W1,
                                                    const float* __restrict__ W2,
                                                    unsigned short* __restrict__ Wt) {
    __shared__ float a[QTR];   // 50 KB: t[s] bins (src-quarter)
    __shared__ int cur[QTR];   // 50 KB: scatter cursors (dst-quarter)
    int bx = blockIdx.x;       // 256 blocks
    int c = bx >> 2, q = bx & 3;
    int base = q * QTR;
    int e0 = c * EPC;

    for (int j = threadIdx.x; j < QTR; j += 1024) {
        a[j] = 0.0f;
        cur[j] = rowst[base + j] + (int)P8[(size_t)c * N_NODES + base + j];
    }
    __syncthreads();

    // ---- single edge sweep: bin by src-quarter, scatter by dst-quarter ----
    for (int e = e0 + threadIdx.x; e < e0 + EPC; e += 1024) {
        int s = src[e], d = dst[e];
        int sq = s - base;
        if ((unsigned)sq < (unsigned)QTR)
            atomicAdd(&a[sq], inorm[d]);       // LDS float atomic (ds_add_f32)
        int dq = d - base;
        if ((unsigned)dq < (unsigned)QTR) {
            int pos = atomicAdd(&cur[dq], 1);  // LDS atomic only
            esrc[pos] = s;
        }
    }
    __syncthreads();
    for (int j = threadIdx.x; j < QTR; j += 1024) {
        float v = a[j];
        if (v != 0.0f) atomicAdd(&qtacc[base + j], v);  // coalesced, L2-resident
    }

    // ---- fused prep tail (grid-stride over the full machine) ----
    int T = gridDim.x * 1024;
    int id0 = bx * 1024 + threadIdx.x;
    for (int i = id0; i < N_NODES * F / 8; i += T) {
        float w = onorm[i >> 4];   // 16 uint2 per 128-col row
        const float4* xv = (const float4*)feat;
        float4 v0 = xv[i * 2], v1 = xv[i * 2 + 1];
        uint2 o;
        o.x = f32x4_to_fp8(v0.x * w, v0.y * w, v0.z * w, v0.w * w);
        o.y = f32x4_to_fp8(v1.x * w, v1.y * w, v1.z * w, v1.w * w);
        xq[i] = o;
    }
    for (int i = id0; i < 2 * F * F; i += T) {
        int wi = i >> 14, rem = i & 16383;
        int n = rem >> 7, k = rem & 127;
        const float* W = wi ? W2 : W1;
        Wt[(size_t)wi * F * F + (size_t)n * F + k] = f2bf(W[k * F + n]);
    }
}

// ---- aggregation: 4 waves/block, 1 dst row/wave; 16 lanes/edge fp8 uint2 ----
__global__ __launch_bounds__(256) void agg_csr_kernel(const uint2* __restrict__ xq,
                                                      uint4* __restrict__ mb,
                                                      const int* __restrict__ rowst,
                                                      const int* __restrict__ esrc,
                                                      const float* __restrict__ inorm) {
    int w = threadIdx.x >> 6;
    int lane = threadIdx.x & 63;
    int g = lane >> 4, t = lane & 15;
    int row = blockIdx.x * 4 + w;
    int beg = __builtin_amdgcn_readfirstlane(rowst[row]);
    int end = __builtin_amdgcn_readfirstlane(rowst[row + 1]);
    float acc[8];
#pragma unroll
    for (int k = 0; k < 8; k++) acc[k] = 0.0f;

    for (int e = beg; e < end; e += 16) {   // clamped, 4 gathers in flight
        int ea = min(e + g,      end - 1);
        int eb = min(e + 4 + g,  end - 1);
        int ec = min(e + 8 + g,  end - 1);
        int ed = min(e + 12 + g, end - 1);
        int sa = esrc[ea], sb = esrc[eb], sc = esrc[ec], sd = esrc[ed];
        uint2 ua = xq[(size_t)sa * 16 + t];
        uint2 ub = xq[(size_t)sb * 16 + t];
        uint2 uc = xq[(size_t)sc * 16 + t];
        uint2 ud = xq[(size_t)sd * 16 + t];
        float wa = (e + g      < end) ? 1.0f : 0.0f;
        float wb = (e + 4 + g  < end) ? 1.0f : 0.0f;
        float wc = (e + 8 + g  < end) ? 1.0f : 0.0f;
        float wd = (e + 12 + g < end) ? 1.0f : 0.0f;
        float fa[8], fb[8], fc[8], fd[8];
        fp8x8_to_f32(ua, fa); fp8x8_to_f32(ub, fb);
        fp8x8_to_f32(uc, fc); fp8x8_to_f32(ud, fd);
#pragma unroll
        for (int k = 0; k < 8; k++)
            acc[k] += fa[k] * wa + fb[k] * wb + fc[k] * wc + fd[k] * wd;
    }
#pragma unroll
    for (int k = 0; k < 8; k++) {
        acc[k] += __shfl_xor(acc[k], 16, 64);
        acc[k] += __shfl_xor(acc[k], 32, 64);
    }
    if (g == 0) {
        float inw = inorm[row];
        uint4 o;
        o.x = packbf2(acc[0] * inw, acc[1] * inw);
        o.y = packbf2(acc[2] * inw, acc[3] * inw);
        o.z = packbf2(acc[4] * inw, acc[5] * inw);
        o.w = packbf2(acc[6] * inw, acc[7] * inw);
        mb[(size_t)row * 16 + t] = o;
    }
}

// ---- MFMA GEMM, single bf16 W staged in LDS (one phase, 64 MFMA) ----
// FINAL=0: Y8 = fp8(onorm[row] * relu(A@W+b))  (layer 1)
// FINAL=1: column sums -> cacc atomics; last block computes out = c@W3+b3
template <int FINAL>
__global__ __launch_bounds__(256) void mfma_gemm_kernel(const unsigned short* __restrict__ A,
                                                        const unsigned short* __restrict__ Wt,
                                                        const float* __restrict__ bias,
                                                        const float* __restrict__ onorm,
                                                        unsigned char* __restrict__ Y8,
                                                        const float* __restrict__ qt,
                                                        float* __restrict__ cacc,
                                                        int* __restrict__ ticket,
                                                        const float* __restrict__ W3,
                                                        const float* __restrict__ b3,
                                                        float* __restrict__ out) {
    __shared__ uint4 sB[F * BSTRIDE];   // 34816 B
    __shared__ float sPf[4][F];         // 2 KB (FINAL only)
    __shared__ int lastFlag;
    int tid = threadIdx.x;
    int w = tid >> 6;
    int lane = tid & 63;
    int quad = lane >> 4, r16 = lane & 15;
    int row0 = blockIdx.x * 64 + w * 16;

    // preload A-frags (global, clamped) so loads overlap staging
    int arow = min(row0 + r16, N_NODES - 1);
    const uint4* Arow = (const uint4*)(A + (size_t)arow * F);
    uint4 a[4];
#pragma unroll
    for (int kk = 0; kk < 4; kk++) a[kk] = Arow[kk * 4 + quad];

    const uint4* G = (const uint4*)Wt;
    for (int j = tid; j < F * 16; j += 256)
        sB[(j >> 4) * BSTRIDE + (j & 15)] = G[j];

    f32x4 acc[8];
#pragma unroll
    for (int t = 0; t < 8; t++) acc[t] = (f32x4){0.f, 0.f, 0.f, 0.f};
    __syncthreads();

#pragma unroll
    for (int kk = 0; kk < 4; kk++) {
        bf16x8 av = __builtin_bit_cast(bf16x8, a[kk]);
#pragma unroll
        for (int t = 0; t < 8; t++) {
            bf16x8 bv = __builtin_bit_cast(bf16x8,
                sB[(t * 16 + r16) * BSTRIDE + kk * 4 + quad]);
            acc[t] = __builtin_amdgcn_mfma_f32_16x16x32_bf16(av, bv, acc[t], 0, 0, 0);
        }
    }

    float rw[4];
#pragma unroll
    for (int reg = 0; reg < 4; reg++) {
        int row = row0 + quad * 4 + reg;
        rw[reg] = (row < N_NODES) ? (FINAL ? qt[row] * onorm[row] : onorm[row]) : 0.0f;
    }

    if (!FINAL) {
#pragma unroll
        for (int t = 0; t < 8; t++) {
            int col = t * 16 + r16;
            float bb = bias[col];
#pragma unroll
            for (int reg = 0; reg < 4; reg++) {
                int row = row0 + quad * 4 + reg;
                if (row < N_NODES) {
                    float v = fmaxf(acc[t][reg] + bb, 0.0f) * rw[reg];
                    unsigned p = __builtin_amdgcn_cvt_pk_fp8_f32(v, v, 0, false);
                    Y8[(size_t)row * F + col] = (unsigned char)(p & 0xFF);
                }
            }
        }
    } else {
#pragma unroll
        for (int t = 0; t < 8; t++) {
            int col = t * 16 + r16;
            float bb = bias[col];
            float p = 0.0f;
#pragma unroll
            for (int reg = 0; reg < 4; reg++)
                p += fmaxf(acc[t][reg] + bb, 0.0f) * rw[reg];
            p += __shfl_xor(p, 16, 64);      // reduce over quad
            p += __shfl_xor(p, 32, 64);
            if (quad == 0) sPf[w][col] = p;
        }
        __syncthreads();
        if (tid < F)
            atomicAdd(&cacc[tid],
                      sPf[0][tid] + sPf[1][tid] + sPf[2][tid] + sPf[3][tid]);
        // last-block-done: compute out = (cacc/N) @ W3 + b3
        __threadfence();
        if (tid == 0) lastFlag = (atomicAdd(ticket, 1) == GB - 1);
        __syncthreads();
        if (lastFlag) {
            if (tid < F) {
                // atomic read-through (bypasses possibly-stale L1)
                float c = atomicAdd(&cacc[tid], 0.0f);
                sPf[0][tid] = c * (1.0f / (float)N_NODES);
            }
            __syncthreads();
            if (tid < F) {
                float o = b3[tid];
                for (int k = 0; k < F; k++) o += sPf[0][k] * W3[k * F + tid];
                out[tid] = o;
            }
        }
    }
}

extern "C" void kernel_launch(void* const* d_in, const int* in_sizes, int n_in,
                              void* d_out, int out_size, void* d_ws, size_t ws_size,
                              hipStream_t stream) {
    const float* feat = (const float*)d_in[0];
    const float* W1   = (const float*)d_in[1];
    const float* b1   = (const float*)d_in[2];
    const float* W2   = (const float*)d_in[3];
    const float* b2   = (const float*)d_in[4];
    const float* W3   = (const float*)d_in[5];
    const float* b3   = (const float*)d_in[6];
    const int*   src  = (const int*)d_in[7];
    const int*   dst  = (const int*)d_in[8];
    float* out = (float*)d_out;

    // workspace layout (~40 MB, 16B-aligned blocks first)
    char* ws = (char*)d_ws;
    size_t off = 0;
    uint4* mb    = (uint4*)(ws + off); off += (size_t)N_NODES * F * 2;       // 12.8 MB bf16
    uint2* xq    = (uint2*)(ws + off); off += (size_t)N_NODES * F;           // 6.4 MB fp8
    uint2* hq    = (uint2*)(ws + off); off += (size_t)N_NODES * F;           // 6.4 MB fp8
    unsigned char* Hs8 = (unsigned char*)(ws + off); off += (size_t)CH * N_NODES;  // 3.2 MB
    unsigned char* Hd8 = (unsigned char*)(ws + off); off += (size_t)CH * N_NODES;  // 3.2 MB
    unsigned char* P8  = (unsigned char*)(ws + off); off += (size_t)CH * N_NODES;  // 3.2 MB
    int*   esrc  = (int*)  (ws + off); off += (size_t)N_EDGES * 4;           // 3.2 MB
    unsigned short* Wt = (unsigned short*)(ws + off); off += 2 * F * F * 2;  // 64 KB bf16
    float* onorm = (float*)(ws + off); off += N_NODES * 4;
    float* inorm = (float*)(ws + off); off += N_NODES * 4;
    float* qtacc = (float*)(ws + off); off += N_NODES * 4;
    int*   rowst = (int*)  (ws + off); off += (N_NODES + 1) * 4;
    int*   bsump = (int*)  (ws + off); off += 2 * CH * SCAN_NB * 4;          // 25 KB
    float* cacc  = (float*)(ws + off); off += F * 4;
    int*   ticket= (int*)  (ws + off); off += 16;

    // CSR build — zero global memsets; qt reduced in-flight via atomics
    hist_kernel<<<4 * CH, 1024, 0, stream>>>(src, dst, Hs8, Hd8, bsump);
    scanC_kernel<<<SCAN_NB, 1024, 0, stream>>>(Hs8, Hd8, bsump, onorm, inorm,
                                               rowst, P8, qtacc, cacc, ticket);
    tqsc_kernel<<<4 * CH, 1024, 0, stream>>>(src, dst, inorm, qtacc, rowst, P8,
                                             esrc, feat, onorm, xq, W1, W2, Wt);

    // layer 1: agg(xq) -> mb (bf16), gemm -> hq (fp8, onorm-prescaled)
    agg_csr_kernel<<<AGG_NB, 256, 0, stream>>>(xq, mb, rowst, esrc, inorm);
    mfma_gemm_kernel<0><<<GB, 256, 0, stream>>>((const unsigned short*)mb, Wt, b1,
                                                onorm, (unsigned char*)hq, qtacc,
                                                cacc, ticket, W3, b3, out);
    // layer 2: agg(hq) -> mb, gemm(+fused colsum + inline final) -> out
    agg_csr_kernel<<<AGG_NB, 256, 0, stream>>>(hq, mb, rowst, esrc, inorm);
    mfma_gemm_kernel<1><<<GB, 256, 0, stream>>>((const unsigned short*)mb, Wt + F * F,
                                                b2, onorm, (unsigned char*)hq, qtacc,
                                                cacc, ticket, W3, b3, out);
}

// Round 11
// 225.421 us; speedup vs baseline: 1.1331x; 1.1331x over previous
//
#include <hip/hip_runtime.h>

// GCN: 3-layer GraphConv (norm='both') + mean over nodes.
// Round 24 (2nd resubmit — R9/R10 benches were GPU-acquisition timeouts):
// R23 post-mortem — cacc column-sum fusion REVERTED (782-deep
// same-address f32 atomics on 8 cache lines serialize in the L2 atomic
// unit: gemm2 went 20 -> 70us at 1% VALU/MFMA = pure stall). part2 +
// final_kernel restored verbatim from R22. KEPT from R23: Tq staging
// deleted — tqsc flushes LDS bins straight into qtacc via spread
// coalesced atomics (50K addresses, 64-deep — measured cheap), scanC
// zeroes qtacc. Dispatches 7 -> 8.
#define N_NODES 50000
#define N_EDGES 800000
#define F 128
#define SCAN_NB 49      // scanC blocks / 1024-node ranges
#define CH 64           // edge chunks (4*CH = 256 blocks)
#define EPC (N_EDGES / CH)   // 12500 edges per chunk
#define HALF 25000      // node half-range (packed 8-bit hist)
#define QTR 12500       // node quarter-range (cursors / float bins)
#define BSTRIDE 17      // uint4 per LDS row (odd -> conflict-free ds_read_b128)
#define AGG_NB (N_NODES / 4)   // 12500 agg blocks (4 waves, 1 row/wave)
#define GB ((N_NODES + 63) / 64)  // 782 gemm blocks

typedef __bf16 bf16x8 __attribute__((ext_vector_type(8)));
typedef float  f32x4  __attribute__((ext_vector_type(4)));
typedef float  f32x2  __attribute__((ext_vector_type(2)));

__device__ inline unsigned short f2bf(float f) {  // RNE fp32 -> bf16 bits
    unsigned u = __float_as_uint(f);
    u += 0x7FFF + ((u >> 16) & 1);
    return (unsigned short)(u >> 16);
}
__device__ inline unsigned packbf2(float a, float b) {
    return (unsigned)f2bf(a) | ((unsigned)f2bf(b) << 16);
}

// ---- fp8 e4m3 (OCP on gfx950) helpers ----
__device__ inline void fp8x8_to_f32(uint2 u, float* f) {
    f32x2 v0 = __builtin_amdgcn_cvt_pk_f32_fp8(u.x, false);
    f32x2 v1 = __builtin_amdgcn_cvt_pk_f32_fp8(u.x, true);
    f32x2 v2 = __builtin_amdgcn_cvt_pk_f32_fp8(u.y, false);
    f32x2 v3 = __builtin_amdgcn_cvt_pk_f32_fp8(u.y, true);
    f[0] = v0.x; f[1] = v0.y; f[2] = v1.x; f[3] = v1.y;
    f[4] = v2.x; f[5] = v2.y; f[6] = v3.x; f[7] = v3.y;
}
__device__ inline unsigned f32x4_to_fp8(float a, float b, float c, float d) {
    unsigned r = __builtin_amdgcn_cvt_pk_fp8_f32(a, b, 0, false);
    r = __builtin_amdgcn_cvt_pk_fp8_f32(c, d, r, true);
    return r;
}

// ---- 8-bit chunked histograms: block = (chunk, type, half) ----
// dst-blocks additionally emit per-1024-node-range partial degree sums
// (bsump[(c*2+h)][r]) for scanC's cross-block prefix base — race-free.
__global__ __launch_bounds__(1024) void hist_kernel(const int* __restrict__ src,
                                                    const int* __restrict__ dst,
                                                    unsigned char* __restrict__ Hs8,
                                                    unsigned char* __restrict__ Hd8,
                                                    int* __restrict__ bsump) {
    __shared__ unsigned hist[HALF / 4];  // 25 KB (4x8-bit packed)
    int bx = blockIdx.x;                 // 256 blocks
    int c = bx >> 2, t = bx & 1, h = (bx >> 1) & 1;
    const int* ids = t ? dst : src;
    unsigned char* H = t ? Hd8 : Hs8;
    int base = h * HALF;
    for (int j = threadIdx.x; j < HALF / 4; j += 1024) hist[j] = 0;
    __syncthreads();
    int e0 = c * EPC;
    for (int e = e0 + threadIdx.x; e < e0 + EPC; e += 1024) {
        int id = ids[e] - base;
        if ((unsigned)id < (unsigned)HALF)
            atomicAdd(&hist[id >> 2], 1u << ((id & 3) * 8));
    }
    __syncthreads();
    unsigned* Hw = (unsigned*)(H + (size_t)c * N_NODES + base);
    for (int j = threadIdx.x; j < HALF / 4; j += 1024) Hw[j] = hist[j];
    if (t) {  // per-range degD partials for the scan base
        int w = threadIdx.x >> 6, lane = threadIdx.x & 63;
        for (int r = w; r < SCAN_NB; r += 16) {
            int gi0 = max(r * 1024, base);
            int gi1 = min(r * 1024 + 1024, base + HALF);
            int s = 0;
            for (int li = gi0 - base + lane; li < gi1 - base; li += 64)
                s += (hist[li >> 2] >> ((li & 3) * 8)) & 255;
#pragma unroll
            for (int off = 32; off; off >>= 1) s += __shfl_down(s, off);
            if (lane == 0) bsump[(c * 2 + h) * SCAN_NB + r] = s;
        }
    }
}

// ---- scanC: degrees + norms + rowst + P8 + qtacc zeroing ----
__global__ __launch_bounds__(1024) void scanC_kernel(const unsigned char* __restrict__ Hs8,
                                                     const unsigned char* __restrict__ Hd8,
                                                     const int* __restrict__ bsump,
                                                     float* __restrict__ onorm,
                                                     float* __restrict__ inorm,
                                                     int* __restrict__ rowst,
                                                     unsigned char* __restrict__ P8,
                                                     float* __restrict__ qtacc) {
    __shared__ int wsum[16];
    __shared__ int tot[SCAN_NB];
    int t = threadIdx.x, lane = t & 63, w = t >> 6;
    int i = blockIdx.x * 1024 + t;
    if (t < SCAN_NB) {  // per-range degD totals (128 partials each)
        int s = 0;
        for (int p = 0; p < 2 * CH; p++) s += bsump[p * SCAN_NB + t];
        tot[t] = s;
    }
    int dd = 0;
    if (i < N_NODES) {
        int ds = 0, run = 0;
        for (int c = 0; c < CH; c++) {
            size_t o = (size_t)c * N_NODES + i;
            ds += Hs8[o];
            P8[o] = (unsigned char)run;   // within-row prefix (<= deg <= 255)
            run += Hd8[o];
        }
        dd = run;
        onorm[i] = rsqrtf(fmaxf((float)ds, 1.0f));
        inorm[i] = rsqrtf(fmaxf((float)dd, 1.0f));
        qtacc[i] = 0.0f;
    }
    int v = dd, incl = v;
#pragma unroll
    for (int off = 1; off < 64; off <<= 1) {
        int u = __shfl_up(incl, off);
        if (lane >= off) incl += u;
    }
    if (lane == 63) wsum[w] = incl;
    __syncthreads();
    if (t == 0) {
        int s = 0;
        for (int r = 0; r < (int)blockIdx.x; r++) s += tot[r];
#pragma unroll
        for (int k = 0; k < 16; k++) { int x = wsum[k]; wsum[k] = s; s += x; }
    }
    __syncthreads();
    incl += wsum[w];
    if (i < N_NODES) {
        rowst[i] = incl - v;           // exclusive prefix
        if (i == N_NODES - 1) rowst[N_NODES] = incl;
    }
}

// ---- tqsc: single-sweep tq-bin + scatter + prep tail: block = (chunk, q) ----
// ONE pass over the chunk's edges; BOTH LDS images live simultaneously:
//   src in quarter q -> float-bin atomicAdd (a[], 50KB)
//   dst in quarter q -> cursor scatter (cur[], 50KB) -> esrc
// Bins flushed via skip-zero COALESCED global f32 atomics into qtacc
// (50K addresses, <=64-deep — measured-cheap regime).
__global__ __launch_bounds__(1024) void tqsc_kernel(const int* __restrict__ src,
                                                    const int* __restrict__ dst,
                                                    const float* __restrict__ inorm,
                                                    float* __restrict__ qtacc,
                                                    const int* __restrict__ rowst,
                                                    const unsigned char* __restrict__ P8,
                                                    int* __restrict__ esrc,
                                                    const float* __restrict__ feat,
                                                    const float* __restrict__ onorm,
                                                    uint2* __restrict__ xq,
                                                    const float* __restrict__ W1,
                                                    const float* __restrict__ W2,
                                                    unsigned short* __restrict__ Wt) {
    __shared__ float a[QTR];   // 50 KB: t[s] bins (src-quarter)
    __shared__ int cur[QTR];   // 50 KB: scatter cursors (dst-quarter)
    int bx = blockIdx.x;       // 256 blocks
    int c = bx >> 2, q = bx & 3;
    int base = q * QTR;
    int e0 = c * EPC;

    for (int j = threadIdx.x; j < QTR; j += 1024) {
        a[j] = 0.0f;
        cur[j] = rowst[base + j] + (int)P8[(size_t)c * N_NODES + base + j];
    }
    __syncthreads();

    // ---- single edge sweep: bin by src-quarter, scatter by dst-quarter ----
    for (int e = e0 + threadIdx.x; e < e0 + EPC; e += 1024) {
        int s = src[e], d = dst[e];
        int sq = s - base;
        if ((unsigned)sq < (unsigned)QTR)
            atomicAdd(&a[sq], inorm[d]);       // LDS float atomic (ds_add_f32)
        int dq = d - base;
        if ((unsigned)dq < (unsigned)QTR) {
            int pos = atomicAdd(&cur[dq], 1);  // LDS atomic only
            esrc[pos] = s;
        }
    }
    __syncthreads();
    for (int j = threadIdx.x; j < QTR; j += 1024) {
        float v = a[j];
        if (v != 0.0f) atomicAdd(&qtacc[base + j], v);  // spread, coalesced
    }

    // ---- fused prep tail (grid-stride over the full machine) ----
    int T = gridDim.x * 1024;
    int id0 = bx * 1024 + threadIdx.x;
    for (int i = id0; i < N_NODES * F / 8; i += T) {
        float w = onorm[i >> 4];   // 16 uint2 per 128-col row
        const float4* xv = (const float4*)feat;
        float4 v0 = xv[i * 2], v1 = xv[i * 2 + 1];
        uint2 o;
        o.x = f32x4_to_fp8(v0.x * w, v0.y * w, v0.z * w, v0.w * w);
        o.y = f32x4_to_fp8(v1.x * w, v1.y * w, v1.z * w, v1.w * w);
        xq[i] = o;
    }
    for (int i = id0; i < 2 * F * F; i += T) {
        int wi = i >> 14, rem = i & 16383;
        int n = rem >> 7, k = rem & 127;
        const float* W = wi ? W2 : W1;
        Wt[(size_t)wi * F * F + (size_t)n * F + k] = f2bf(W[k * F + n]);
    }
}

// ---- aggregation: 4 waves/block, 1 dst row/wave; 16 lanes/edge fp8 uint2 ----
__global__ __launch_bounds__(256) void agg_csr_kernel(const uint2* __restrict__ xq,
                                                      uint4* __restrict__ mb,
                                                      const int* __restrict__ rowst,
                                                      const int* __restrict__ esrc,
                                                      const float* __restrict__ inorm) {
    int w = threadIdx.x >> 6;
    int lane = threadIdx.x & 63;
    int g = lane >> 4, t = lane & 15;
    int row = blockIdx.x * 4 + w;
    int beg = __builtin_amdgcn_readfirstlane(rowst[row]);
    int end = __builtin_amdgcn_readfirstlane(rowst[row + 1]);
    float acc[8];
#pragma unroll
    for (int k = 0; k < 8; k++) acc[k] = 0.0f;

    for (int e = beg; e < end; e += 16) {   // clamped, 4 gathers in flight
        int ea = min(e + g,      end - 1);
        int eb = min(e + 4 + g,  end - 1);
        int ec = min(e + 8 + g,  end - 1);
        int ed = min(e + 12 + g, end - 1);
        int sa = esrc[ea], sb = esrc[eb], sc = esrc[ec], sd = esrc[ed];
        uint2 ua = xq[(size_t)sa * 16 + t];
        uint2 ub = xq[(size_t)sb * 16 + t];
        uint2 uc = xq[(size_t)sc * 16 + t];
        uint2 ud = xq[(size_t)sd * 16 + t];
        float wa = (e + g      < end) ? 1.0f : 0.0f;
        float wb = (e + 4 + g  < end) ? 1.0f : 0.0f;
        float wc = (e + 8 + g  < end) ? 1.0f : 0.0f;
        float wd = (e + 12 + g < end) ? 1.0f : 0.0f;
        float fa[8], fb[8], fc[8], fd[8];
        fp8x8_to_f32(ua, fa); fp8x8_to_f32(ub, fb);
        fp8x8_to_f32(uc, fc); fp8x8_to_f32(ud, fd);
#pragma unroll
        for (int k = 0; k < 8; k++)
            acc[k] += fa[k] * wa + fb[k] * wb + fc[k] * wc + fd[k] * wd;
    }
#pragma unroll
    for (int k = 0; k < 8; k++) {
        acc[k] += __shfl_xor(acc[k], 16, 64);
        acc[k] += __shfl_xor(acc[k], 32, 64);
    }
    if (g == 0) {
        float inw = inorm[row];
        uint4 o;
        o.x = packbf2(acc[0] * inw, acc[1] * inw);
        o.y = packbf2(acc[2] * inw, acc[3] * inw);
        o.z = packbf2(acc[4] * inw, acc[5] * inw);
        o.w = packbf2(acc[6] * inw, acc[7] * inw);
        mb[(size_t)row * 16 + t] = o;
    }
}

// ---- MFMA GEMM, single bf16 W staged in LDS (one phase, 64 MFMA) ----
// FINAL=0: Y8 = fp8(onorm[row] * relu(A@W+b))  (layer 1)
// FINAL=1: no Y8; part2[block][col] = sum_rows qt[row]*onorm[row]*relu(...)
template <int FINAL>
__global__ __launch_bounds__(256) void mfma_gemm_kernel(const unsigned short* __restrict__ A,
                                                        const unsigned short* __restrict__ Wt,
                                                        const float* __restrict__ bias,
                                                        const float* __restrict__ onorm,
                                                        unsigned char* __restrict__ Y8,
                                                        const float* __restrict__ qt,
                                                        float* __restrict__ part2) {
    __shared__ uint4 sB[F * BSTRIDE];   // 34816 B
    __shared__ float sPf[4][F];         // 2 KB (FINAL only)
    int tid = threadIdx.x;
    int w = tid >> 6;
    int lane = tid & 63;
    int quad = lane >> 4, r16 = lane & 15;
    int row0 = blockIdx.x * 64 + w * 16;

    // preload A-frags (global, clamped) so loads overlap staging
    int arow = min(row0 + r16, N_NODES - 1);
    const uint4* Arow = (const uint4*)(A + (size_t)arow * F);
    uint4 a[4];
#pragma unroll
    for (int kk = 0; kk < 4; kk++) a[kk] = Arow[kk * 4 + quad];

    const uint4* G = (const uint4*)Wt;
    for (int j = tid; j < F * 16; j += 256)
        sB[(j >> 4) * BSTRIDE + (j & 15)] = G[j];

    f32x4 acc[8];
#pragma unroll
    for (int t = 0; t < 8; t++) acc[t] = (f32x4){0.f, 0.f, 0.f, 0.f};
    __syncthreads();

#pragma unroll
    for (int kk = 0; kk < 4; kk++) {
        bf16x8 av = __builtin_bit_cast(bf16x8, a[kk]);
#pragma unroll
        for (int t = 0; t < 8; t++) {
            bf16x8 bv = __builtin_bit_cast(bf16x8,
                sB[(t * 16 + r16) * BSTRIDE + kk * 4 + quad]);
            acc[t] = __builtin_amdgcn_mfma_f32_16x16x32_bf16(av, bv, acc[t], 0, 0, 0);
        }
    }

    float rw[4];
#pragma unroll
    for (int reg = 0; reg < 4; reg++) {
        int row = row0 + quad * 4 + reg;
        rw[reg] = (row < N_NODES) ? (FINAL ? qt[row] * onorm[row] : onorm[row]) : 0.0f;
    }

    if (!FINAL) {
#pragma unroll
        for (int t = 0; t < 8; t++) {
            int col = t * 16 + r16;
            float bb = bias[col];
#pragma unroll
            for (int reg = 0; reg < 4; reg++) {
                int row = row0 + quad * 4 + reg;
                if (row < N_NODES) {
                    float v = fmaxf(acc[t][reg] + bb, 0.0f) * rw[reg];
                    unsigned p = __builtin_amdgcn_cvt_pk_fp8_f32(v, v, 0, false);
                    Y8[(size_t)row * F + col] = (unsigned char)(p & 0xFF);
                }
            }
        }
    } else {
#pragma unroll
        for (int t = 0; t < 8; t++) {
            int col = t * 16 + r16;
            float bb = bias[col];
            float p = 0.0f;
#pragma unroll
            for (int reg = 0; reg < 4; reg++)
                p += fmaxf(acc[t][reg] + bb, 0.0f) * rw[reg];
            p += __shfl_xor(p, 16, 64);      // reduce over quad
            p += __shfl_xor(p, 32, 64);
            if (quad == 0) sPf[w][col] = p;
        }
        __syncthreads();
        if (tid < F)
            part2[(size_t)blockIdx.x * F + tid] =
                sPf[0][tid] + sPf[1][tid] + sPf[2][tid] + sPf[3][tid];
    }
}

// ---- final: c = (1/N) * sum_b part2[b] (b < GB), out = c @ W3 + b3 ----
__global__ __launch_bounds__(1024) void final_kernel(const float* __restrict__ part2,
                                                     const float* __restrict__ W3,
                                                     const float* __restrict__ b3,
                                                     float* __restrict__ out) {
    __shared__ float sc[8][F];  // 4 KB
    int tid = threadIdx.x;
    int col = tid & 127, sl = tid >> 7;
    float acc = 0.0f;
    for (int b = sl; b < GB; b += 8) acc += part2[(size_t)b * F + col];
    sc[sl][col] = acc;
    __syncthreads();
    if (tid < F) {
        float s = 0.0f;
#pragma unroll
        for (int k = 0; k < 8; k++) s += sc[k][tid];
        sc[0][tid] = s * (1.0f / (float)N_NODES);
    }
    __syncthreads();
    if (tid < F) {
        float o = b3[tid];
        for (int k = 0; k < F; k++) o += sc[0][k] * W3[k * F + tid];
        out[tid] = o;
    }
}

extern "C" void kernel_launch(void* const* d_in, const int* in_sizes, int n_in,
                              void* d_out, int out_size, void* d_ws, size_t ws_size,
                              hipStream_t stream) {
    const float* feat = (const float*)d_in[0];
    const float* W1   = (const float*)d_in[1];
    const float* b1   = (const float*)d_in[2];
    const float* W2   = (const float*)d_in[3];
    const float* b2   = (const float*)d_in[4];
    const float* W3   = (const float*)d_in[5];
    const float* b3   = (const float*)d_in[6];
    const int*   src  = (const int*)d_in[7];
    const int*   dst  = (const int*)d_in[8];
    float* out = (float*)d_out;

    // workspace layout (~40 MB, 16B-aligned blocks first)
    char* ws = (char*)d_ws;
    size_t off = 0;
    uint4* mb    = (uint4*)(ws + off); off += (size_t)N_NODES * F * 2;       // 12.8 MB bf16
    uint2* xq    = (uint2*)(ws + off); off += (size_t)N_NODES * F;           // 6.4 MB fp8
    uint2* hq    = (uint2*)(ws + off); off += (size_t)N_NODES * F;           // 6.4 MB fp8
    unsigned char* Hs8 = (unsigned char*)(ws + off); off += (size_t)CH * N_NODES;  // 3.2 MB
    unsigned char* Hd8 = (unsigned char*)(ws + off); off += (size_t)CH * N_NODES;  // 3.2 MB
    unsigned char* P8  = (unsigned char*)(ws + off); off += (size_t)CH * N_NODES;  // 3.2 MB
    int*   esrc  = (int*)  (ws + off); off += (size_t)N_EDGES * 4;           // 3.2 MB
    unsigned short* Wt = (unsigned short*)(ws + off); off += 2 * F * F * 2;  // 64 KB bf16
    float* part2 = (float*)(ws + off); off += (size_t)GB * F * 4;            // 400 KB
    float* onorm = (float*)(ws + off); off += N_NODES * 4;
    float* inorm = (float*)(ws + off); off += N_NODES * 4;
    float* qtacc = (float*)(ws + off); off += N_NODES * 4;
    int*   rowst = (int*)  (ws + off); off += (N_NODES + 1) * 4;
    int*   bsump = (int*)  (ws + off); off += 2 * CH * SCAN_NB * 4;          // 25 KB

    // CSR build — qt reduced in-flight via spread coalesced atomics
    hist_kernel<<<4 * CH, 1024, 0, stream>>>(src, dst, Hs8, Hd8, bsump);
    scanC_kernel<<<SCAN_NB, 1024, 0, stream>>>(Hs8, Hd8, bsump, onorm, inorm,
                                               rowst, P8, qtacc);
    tqsc_kernel<<<4 * CH, 1024, 0, stream>>>(src, dst, inorm, qtacc, rowst, P8,
                                             esrc, feat, onorm, xq, W1, W2, Wt);

    // layer 1: agg(xq) -> mb (bf16), gemm -> hq (fp8, onorm-prescaled)
    agg_csr_kernel<<<AGG_NB, 256, 0, stream>>>(xq, mb, rowst, esrc, inorm);
    mfma_gemm_kernel<0><<<GB, 256, 0, stream>>>((const unsigned short*)mb, Wt, b1,
                                                onorm, (unsigned char*)hq, qtacc, part2);
    // layer 2: agg(hq) -> mb, gemm(+fused layer-3 column sum) -> part2
    agg_csr_kernel<<<AGG_NB, 256, 0, stream>>>(hq, mb, rowst, esrc, inorm);
    mfma_gemm_kernel<1><<<GB, 256, 0, stream>>>((const unsigned short*)mb, Wt + F * F,
                                                b2, onorm, (unsigned char*)hq, qtacc, part2);
    // final: c = (1/N) sum_b part2[b]; out = c @ W3 + b3
    final_kernel<<<1, 1024, 0, stream>>>(part2, W3, b3, out);
}

// Round 12
// 219.578 us; speedup vs baseline: 1.1632x; 1.0266x over previous
//
#include <hip/hip_runtime.h>

// GCN: 3-layer GraphConv (norm='both') + mean over nodes.
// Round 25: R24's qtacc atomic flush REVERTED (measured +8us vs Tq
// staging: 2M spread f32 RMW atomics ~7-13us > 25.6MB streaming ~4-5us.
// Atomic law: scattered=terrible, deep-contention=terrible, spread-
// coalesced=mediocre — streaming still wins). Base = R22 (217.4us best).
// NEW: XCD-locality block remap in hist/tqsc — chunk c's sibling blocks
// now at bx = c + 64k, all = c (mod 8) -> same XCD; the chunk's 100KB
// edge slice is fetched once per XCD instead of 4x across XCDs.
#define N_NODES 50000
#define N_EDGES 800000
#define F 128
#define SCAN_NB 49      // scanC blocks / 1024-node ranges
#define CH 64           // edge chunks (4*CH = 256 blocks)
#define EPC (N_EDGES / CH)   // 12500 edges per chunk
#define HALF 25000      // node half-range (packed 8-bit hist)
#define QTR 12500       // node quarter-range (cursors / float bins)
#define BSTRIDE 17      // uint4 per LDS row (odd -> conflict-free ds_read_b128)
#define AGG_NB (N_NODES / 4)   // 12500 agg blocks (4 waves, 1 row/wave)
#define GB ((N_NODES + 63) / 64)  // 782 gemm blocks

typedef __bf16 bf16x8 __attribute__((ext_vector_type(8)));
typedef float  f32x4  __attribute__((ext_vector_type(4)));
typedef float  f32x2  __attribute__((ext_vector_type(2)));

__device__ inline unsigned short f2bf(float f) {  // RNE fp32 -> bf16 bits
    unsigned u = __float_as_uint(f);
    u += 0x7FFF + ((u >> 16) & 1);
    return (unsigned short)(u >> 16);
}
__device__ inline unsigned packbf2(float a, float b) {
    return (unsigned)f2bf(a) | ((unsigned)f2bf(b) << 16);
}

// ---- fp8 e4m3 (OCP on gfx950) helpers ----
__device__ inline void fp8x8_to_f32(uint2 u, float* f) {
    f32x2 v0 = __builtin_amdgcn_cvt_pk_f32_fp8(u.x, false);
    f32x2 v1 = __builtin_amdgcn_cvt_pk_f32_fp8(u.x, true);
    f32x2 v2 = __builtin_amdgcn_cvt_pk_f32_fp8(u.y, false);
    f32x2 v3 = __builtin_amdgcn_cvt_pk_f32_fp8(u.y, true);
    f[0] = v0.x; f[1] = v0.y; f[2] = v1.x; f[3] = v1.y;
    f[4] = v2.x; f[5] = v2.y; f[6] = v3.x; f[7] = v3.y;
}
__device__ inline unsigned f32x4_to_fp8(float a, float b, float c, float d) {
    unsigned r = __builtin_amdgcn_cvt_pk_fp8_f32(a, b, 0, false);
    r = __builtin_amdgcn_cvt_pk_fp8_f32(c, d, r, true);
    return r;
}

// ---- 8-bit chunked histograms: block remap (c = bx&63) for XCD locality ----
// Siblings of chunk c at bx = c+64k share XCD c%8 -> chunk edge slice is
// L2-resident after the first touch. dst-blocks additionally emit
// per-1024-node-range partial degree sums (bsump) — race-free.
__global__ __launch_bounds__(1024) void hist_kernel(const int* __restrict__ src,
                                                    const int* __restrict__ dst,
                                                    unsigned char* __restrict__ Hs8,
                                                    unsigned char* __restrict__ Hd8,
                                                    int* __restrict__ bsump) {
    __shared__ unsigned hist[HALF / 4];  // 25 KB (4x8-bit packed)
    int bx = blockIdx.x;                 // 256 blocks
    int c = bx & 63, t = (bx >> 6) & 1, h = bx >> 7;
    const int* ids = t ? dst : src;
    unsigned char* H = t ? Hd8 : Hs8;
    int base = h * HALF;
    for (int j = threadIdx.x; j < HALF / 4; j += 1024) hist[j] = 0;
    __syncthreads();
    int e0 = c * EPC;
    for (int e = e0 + threadIdx.x; e < e0 + EPC; e += 1024) {
        int id = ids[e] - base;
        if ((unsigned)id < (unsigned)HALF)
            atomicAdd(&hist[id >> 2], 1u << ((id & 3) * 8));
    }
    __syncthreads();
    unsigned* Hw = (unsigned*)(H + (size_t)c * N_NODES + base);
    for (int j = threadIdx.x; j < HALF / 4; j += 1024) Hw[j] = hist[j];
    if (t) {  // per-range degD partials for the scan base
        int w = threadIdx.x >> 6, lane = threadIdx.x & 63;
        for (int r = w; r < SCAN_NB; r += 16) {
            int gi0 = max(r * 1024, base);
            int gi1 = min(r * 1024 + 1024, base + HALF);
            int s = 0;
            for (int li = gi0 - base + lane; li < gi1 - base; li += 64)
                s += (hist[li >> 2] >> ((li & 3) * 8)) & 255;
#pragma unroll
            for (int off = 32; off; off >>= 1) s += __shfl_down(s, off);
            if (lane == 0) bsump[(c * 2 + h) * SCAN_NB + r] = s;
        }
    }
}

// ---- scanC: degrees + norms + rowst + P8 in ONE chunk loop (49 x 1024) ----
__global__ __launch_bounds__(1024) void scanC_kernel(const unsigned char* __restrict__ Hs8,
                                                     const unsigned char* __restrict__ Hd8,
                                                     const int* __restrict__ bsump,
                                                     float* __restrict__ onorm,
                                                     float* __restrict__ inorm,
                                                     int* __restrict__ rowst,
                                                     unsigned char* __restrict__ P8) {
    __shared__ int wsum[16];
    __shared__ int tot[SCAN_NB];
    int t = threadIdx.x, lane = t & 63, w = t >> 6;
    int i = blockIdx.x * 1024 + t;
    if (t < SCAN_NB) {  // per-range degD totals (128 partials each)
        int s = 0;
        for (int p = 0; p < 2 * CH; p++) s += bsump[p * SCAN_NB + t];
        tot[t] = s;
    }
    int dd = 0;
    if (i < N_NODES) {
        int ds = 0, run = 0;
        for (int c = 0; c < CH; c++) {
            size_t o = (size_t)c * N_NODES + i;
            ds += Hs8[o];
            P8[o] = (unsigned char)run;   // within-row prefix (<= deg <= 255)
            run += Hd8[o];
        }
        dd = run;
        onorm[i] = rsqrtf(fmaxf((float)ds, 1.0f));
        inorm[i] = rsqrtf(fmaxf((float)dd, 1.0f));
    }
    int v = dd, incl = v;
#pragma unroll
    for (int off = 1; off < 64; off <<= 1) {
        int u = __shfl_up(incl, off);
        if (lane >= off) incl += u;
    }
    if (lane == 63) wsum[w] = incl;
    __syncthreads();
    if (t == 0) {
        int s = 0;
        for (int r = 0; r < (int)blockIdx.x; r++) s += tot[r];
#pragma unroll
        for (int k = 0; k < 16; k++) { int x = wsum[k]; wsum[k] = s; s += x; }
    }
    __syncthreads();
    incl += wsum[w];
    if (i < N_NODES) {
        rowst[i] = incl - v;           // exclusive prefix
        if (i == N_NODES - 1) rowst[N_NODES] = incl;
    }
}

// ---- tqsc: single-sweep tq-bin + scatter + prep tail; XCD-local remap ----
// Block decode c = bx&63, q = bx>>6: chunk c's 4 quarter-blocks share XCD
// c%8 -> 3 of 4 chunk edge reads become L2 hits. ONE pass over the
// chunk's edges; BOTH LDS images live simultaneously:
//   src in quarter q -> float-bin atomicAdd (a[], 50KB) -> Tq
//   dst in quarter q -> cursor scatter (cur[], 50KB) -> esrc
__global__ __launch_bounds__(1024) void tqsc_kernel(const int* __restrict__ src,
                                                    const int* __restrict__ dst,
                                                    const float* __restrict__ inorm,
                                                    float* __restrict__ Tq,
                                                    const int* __restrict__ rowst,
                                                    const unsigned char* __restrict__ P8,
                                                    int* __restrict__ esrc,
                                                    const float* __restrict__ feat,
                                                    const float* __restrict__ onorm,
                                                    uint2* __restrict__ xq,
                                                    const float* __restrict__ W1,
                                                    const float* __restrict__ W2,
                                                    unsigned short* __restrict__ Wt) {
    __shared__ float a[QTR];   // 50 KB: t[s] bins (src-quarter)
    __shared__ int cur[QTR];   // 50 KB: scatter cursors (dst-quarter)
    int bx = blockIdx.x;       // 256 blocks
    int c = bx & 63, q = bx >> 6;
    int base = q * QTR;
    int e0 = c * EPC;

    for (int j = threadIdx.x; j < QTR; j += 1024) {
        a[j] = 0.0f;
        cur[j] = rowst[base + j] + (int)P8[(size_t)c * N_NODES + base + j];
    }
    __syncthreads();

    // ---- single edge sweep: bin by src-quarter, scatter by dst-quarter ----
    for (int e = e0 + threadIdx.x; e < e0 + EPC; e += 1024) {
        int s = src[e], d = dst[e];
        int sq = s - base;
        if ((unsigned)sq < (unsigned)QTR)
            atomicAdd(&a[sq], inorm[d]);       // LDS float atomic (ds_add_f32)
        int dq = d - base;
        if ((unsigned)dq < (unsigned)QTR) {
            int pos = atomicAdd(&cur[dq], 1);  // LDS atomic only
            esrc[pos] = s;
        }
    }
    __syncthreads();
    for (int j = threadIdx.x; j < QTR; j += 1024)
        Tq[(size_t)c * N_NODES + base + j] = a[j];

    // ---- fused prep tail (grid-stride over the full machine) ----
    int T = gridDim.x * 1024;
    int id0 = bx * 1024 + threadIdx.x;
    for (int i = id0; i < N_NODES * F / 8; i += T) {
        float w = onorm[i >> 4];   // 16 uint2 per 128-col row
        const float4* xv = (const float4*)feat;
        float4 v0 = xv[i * 2], v1 = xv[i * 2 + 1];
        uint2 o;
        o.x = f32x4_to_fp8(v0.x * w, v0.y * w, v0.z * w, v0.w * w);
        o.y = f32x4_to_fp8(v1.x * w, v1.y * w, v1.z * w, v1.w * w);
        xq[i] = o;
    }
    for (int i = id0; i < 2 * F * F; i += T) {
        int wi = i >> 14, rem = i & 16383;
        int n = rem >> 7, k = rem & 127;
        const float* W = wi ? W2 : W1;
        Wt[(size_t)wi * F * F + (size_t)n * F + k] = f2bf(W[k * F + n]);
    }
}

// ---- aggregation: 4 waves/block, 1 dst row/wave; 16 lanes/edge fp8 uint2 ----
// QT=1: tail computes qt[i] = sum_c Tq[c][i]
template <int QT>
__global__ __launch_bounds__(256) void agg_csr_kernel(const uint2* __restrict__ xq,
                                                      uint4* __restrict__ mb,
                                                      const int* __restrict__ rowst,
                                                      const int* __restrict__ esrc,
                                                      const float* __restrict__ inorm,
                                                      const float* __restrict__ Tq,
                                                      float* __restrict__ qt) {
    int w = threadIdx.x >> 6;
    int lane = threadIdx.x & 63;
    int g = lane >> 4, t = lane & 15;
    int row = blockIdx.x * 4 + w;
    int beg = __builtin_amdgcn_readfirstlane(rowst[row]);
    int end = __builtin_amdgcn_readfirstlane(rowst[row + 1]);
    float acc[8];
#pragma unroll
    for (int k = 0; k < 8; k++) acc[k] = 0.0f;

    for (int e = beg; e < end; e += 16) {   // clamped, 4 gathers in flight
        int ea = min(e + g,      end - 1);
        int eb = min(e + 4 + g,  end - 1);
        int ec = min(e + 8 + g,  end - 1);
        int ed = min(e + 12 + g, end - 1);
        int sa = esrc[ea], sb = esrc[eb], sc = esrc[ec], sd = esrc[ed];
        uint2 ua = xq[(size_t)sa * 16 + t];
        uint2 ub = xq[(size_t)sb * 16 + t];
        uint2 uc = xq[(size_t)sc * 16 + t];
        uint2 ud = xq[(size_t)sd * 16 + t];
        float wa = (e + g      < end) ? 1.0f : 0.0f;
        float wb = (e + 4 + g  < end) ? 1.0f : 0.0f;
        float wc = (e + 8 + g  < end) ? 1.0f : 0.0f;
        float wd = (e + 12 + g < end) ? 1.0f : 0.0f;
        float fa[8], fb[8], fc[8], fd[8];
        fp8x8_to_f32(ua, fa); fp8x8_to_f32(ub, fb);
        fp8x8_to_f32(uc, fc); fp8x8_to_f32(ud, fd);
#pragma unroll
        for (int k = 0; k < 8; k++)
            acc[k] += fa[k] * wa + fb[k] * wb + fc[k] * wc + fd[k] * wd;
    }
#pragma unroll
    for (int k = 0; k < 8; k++) {
        acc[k] += __shfl_xor(acc[k], 16, 64);
        acc[k] += __shfl_xor(acc[k], 32, 64);
    }
    if (g == 0) {
        float inw = inorm[row];
        uint4 o;
        o.x = packbf2(acc[0] * inw, acc[1] * inw);
        o.y = packbf2(acc[2] * inw, acc[3] * inw);
        o.z = packbf2(acc[4] * inw, acc[5] * inw);
        o.w = packbf2(acc[6] * inw, acc[7] * inw);
        mb[(size_t)row * 16 + t] = o;
    }
    if (QT) {  // qt[i] = sum_c Tq[c][i]
        int i = blockIdx.x * 256 + threadIdx.x;
        if (i < N_NODES) {
            float s = 0.0f;
            for (int c = 0; c < CH; c++) s += Tq[(size_t)c * N_NODES + i];
            qt[i] = s;
        }
    }
}

// ---- MFMA GEMM, single bf16 W staged in LDS (one phase, 64 MFMA) ----
// FINAL=0: Y8 = fp8(onorm[row] * relu(A@W+b))  (layer 1)
// FINAL=1: no Y8; part2[block][col] = sum_rows qt[row]*onorm[row]*relu(...)
template <int FINAL>
__global__ __launch_bounds__(256) void mfma_gemm_kernel(const unsigned short* __restrict__ A,
                                                        const unsigned short* __restrict__ Wt,
                                                        const float* __restrict__ bias,
                                                        const float* __restrict__ onorm,
                                                        unsigned char* __restrict__ Y8,
                                                        const float* __restrict__ qt,
                                                        float* __restrict__ part2) {
    __shared__ uint4 sB[F * BSTRIDE];   // 34816 B
    __shared__ float sPf[4][F];         // 2 KB (FINAL only)
    int tid = threadIdx.x;
    int w = tid >> 6;
    int lane = tid & 63;
    int quad = lane >> 4, r16 = lane & 15;
    int row0 = blockIdx.x * 64 + w * 16;

    // preload A-frags (global, clamped) so loads overlap staging
    int arow = min(row0 + r16, N_NODES - 1);
    const uint4* Arow = (const uint4*)(A + (size_t)arow * F);
    uint4 a[4];
#pragma unroll
    for (int kk = 0; kk < 4; kk++) a[kk] = Arow[kk * 4 + quad];

    const uint4* G = (const uint4*)Wt;
    for (int j = tid; j < F * 16; j += 256)
        sB[(j >> 4) * BSTRIDE + (j & 15)] = G[j];

    f32x4 acc[8];
#pragma unroll
    for (int t = 0; t < 8; t++) acc[t] = (f32x4){0.f, 0.f, 0.f, 0.f};
    __syncthreads();

#pragma unroll
    for (int kk = 0; kk < 4; kk++) {
        bf16x8 av = __builtin_bit_cast(bf16x8, a[kk]);
#pragma unroll
        for (int t = 0; t < 8; t++) {
            bf16x8 bv = __builtin_bit_cast(bf16x8,
                sB[(t * 16 + r16) * BSTRIDE + kk * 4 + quad]);
            acc[t] = __builtin_amdgcn_mfma_f32_16x16x32_bf16(av, bv, acc[t], 0, 0, 0);
        }
    }

    float rw[4];
#pragma unroll
    for (int reg = 0; reg < 4; reg++) {
        int row = row0 + quad * 4 + reg;
        rw[reg] = (row < N_NODES) ? (FINAL ? qt[row] * onorm[row] : onorm[row]) : 0.0f;
    }

    if (!FINAL) {
#pragma unroll
        for (int t = 0; t < 8; t++) {
            int col = t * 16 + r16;
            float bb = bias[col];
#pragma unroll
            for (int reg = 0; reg < 4; reg++) {
                int row = row0 + quad * 4 + reg;
                if (row < N_NODES) {
                    float v = fmaxf(acc[t][reg] + bb, 0.0f) * rw[reg];
                    unsigned p = __builtin_amdgcn_cvt_pk_fp8_f32(v, v, 0, false);
                    Y8[(size_t)row * F + col] = (unsigned char)(p & 0xFF);
                }
            }
        }
    } else {
#pragma unroll
        for (int t = 0; t < 8; t++) {
            int col = t * 16 + r16;
            float bb = bias[col];
            float p = 0.0f;
#pragma unroll
            for (int reg = 0; reg < 4; reg++)
                p += fmaxf(acc[t][reg] + bb, 0.0f) * rw[reg];
            p += __shfl_xor(p, 16, 64);      // reduce over quad
            p += __shfl_xor(p, 32, 64);
            if (quad == 0) sPf[w][col] = p;
        }
        __syncthreads();
        if (tid < F)
            part2[(size_t)blockIdx.x * F + tid] =
                sPf[0][tid] + sPf[1][tid] + sPf[2][tid] + sPf[3][tid];
    }
}

// ---- final: c = (1/N) * sum_b part2[b] (b < GB), out = c @ W3 + b3 ----
__global__ __launch_bounds__(1024) void final_kernel(const float* __restrict__ part2,
                                                     const float* __restrict__ W3,
                                                     const float* __restrict__ b3,
                                                     float* __restrict__ out) {
    __shared__ float sc[8][F];  // 4 KB
    int tid = threadIdx.x;
    int col = tid & 127, sl = tid >> 7;
    float acc = 0.0f;
    for (int b = sl; b < GB; b += 8) acc += part2[(size_t)b * F + col];
    sc[sl][col] = acc;
    __syncthreads();
    if (tid < F) {
        float s = 0.0f;
#pragma unroll
        for (int k = 0; k < 8; k++) s += sc[k][tid];
        sc[0][tid] = s * (1.0f / (float)N_NODES);
    }
    __syncthreads();
    if (tid < F) {
        float o = b3[tid];
        for (int k = 0; k < F; k++) o += sc[0][k] * W3[k * F + tid];
        out[tid] = o;
    }
}

extern "C" void kernel_launch(void* const* d_in, const int* in_sizes, int n_in,
                              void* d_out, int out_size, void* d_ws, size_t ws_size,
                              hipStream_t stream) {
    const float* feat = (const float*)d_in[0];
    const float* W1   = (const float*)d_in[1];
    const float* b1   = (const float*)d_in[2];
    const float* W2   = (const float*)d_in[3];
    const float* b2   = (const float*)d_in[4];
    const float* W3   = (const float*)d_in[5];
    const float* b3   = (const float*)d_in[6];
    const int*   src  = (const int*)d_in[7];
    const int*   dst  = (const int*)d_in[8];
    float* out = (float*)d_out;

    // workspace layout (~53 MB, 16B-aligned blocks first)
    char* ws = (char*)d_ws;
    size_t off = 0;
    uint4* mb    = (uint4*)(ws + off); off += (size_t)N_NODES * F * 2;       // 12.8 MB bf16
    float* Tq    = (float*)(ws + off); off += (size_t)CH * N_NODES * 4;      // 12.8 MB
    uint2* xq    = (uint2*)(ws + off); off += (size_t)N_NODES * F;           // 6.4 MB fp8
    uint2* hq    = (uint2*)(ws + off); off += (size_t)N_NODES * F;           // 6.4 MB fp8
    unsigned char* Hs8 = (unsigned char*)(ws + off); off += (size_t)CH * N_NODES;  // 3.2 MB
    unsigned char* Hd8 = (unsigned char*)(ws + off); off += (size_t)CH * N_NODES;  // 3.2 MB
    unsigned char* P8  = (unsigned char*)(ws + off); off += (size_t)CH * N_NODES;  // 3.2 MB
    int*   esrc  = (int*)  (ws + off); off += (size_t)N_EDGES * 4;           // 3.2 MB
    unsigned short* Wt = (unsigned short*)(ws + off); off += 2 * F * F * 2;  // 64 KB bf16
    float* part2 = (float*)(ws + off); off += (size_t)GB * F * 4;            // 400 KB
    float* onorm = (float*)(ws + off); off += N_NODES * 4;
    float* inorm = (float*)(ws + off); off += N_NODES * 4;
    float* qt    = (float*)(ws + off); off += N_NODES * 4;
    int*   rowst = (int*)  (ws + off); off += (N_NODES + 1) * 4;
    int*   bsump = (int*)  (ws + off); off += 2 * CH * SCAN_NB * 4;          // 25 KB

    // CSR build — zero global atomics, zero memsets
    hist_kernel<<<4 * CH, 1024, 0, stream>>>(src, dst, Hs8, Hd8, bsump);
    scanC_kernel<<<SCAN_NB, 1024, 0, stream>>>(Hs8, Hd8, bsump, onorm, inorm,
                                               rowst, P8);
    tqsc_kernel<<<4 * CH, 1024, 0, stream>>>(src, dst, inorm, Tq, rowst, P8,
                                             esrc, feat, onorm, xq, W1, W2, Wt);

    // layer 1: agg(xq) -> mb (bf16, + qt tail), gemm -> hq (fp8, onorm-prescaled)
    agg_csr_kernel<1><<<AGG_NB, 256, 0, stream>>>(xq, mb, rowst, esrc, inorm, Tq, qt);
    mfma_gemm_kernel<0><<<GB, 256, 0, stream>>>((const unsigned short*)mb, Wt, b1,
                                                onorm, (unsigned char*)hq, qt, part2);
    // layer 2: agg(hq) -> mb, gemm(+fused layer-3 column sum) -> part2
    agg_csr_kernel<0><<<AGG_NB, 256, 0, stream>>>(hq, mb, rowst, esrc, inorm, Tq, qt);
    mfma_gemm_kernel<1><<<GB, 256, 0, stream>>>((const unsigned short*)mb, Wt + F * F,
                                                b2, onorm, (unsigned char*)hq, qt, part2);
    // final: c = (1/N) sum_b part2[b]; out = c @ W3 + b3
    final_kernel<<<1, 1024, 0, stream>>>(part2, W3, b3, out);
}

// Round 13
// 212.385 us; speedup vs baseline: 1.2026x; 1.0339x over previous
//
#include <hip/hip_runtime.h>

// GCN: 3-layer GraphConv (norm='both') + mean over nodes.
// Round 26: base = R22 (217.4us best; R25's XCD remap reverted — measured
// neutral, L3 already absorbed cross-XCD re-reads). NEW: int4-vectorized
// edge loads in the two edge sweeps (hist, tqsc): loop trips 12.2 -> 3.05
// per block, same LDS atomics but 4x fewer loads/branches/addr-calc, and
// 4 independent atomics per trip for latency overlap. Edge order within
// a dst row is permuted (harmless: agg sums, esrc row content is a set).
#define N_NODES 50000
#define N_EDGES 800000
#define F 128
#define SCAN_NB 49      // scanC blocks / 1024-node ranges
#define CH 64           // edge chunks (4*CH = 256 blocks)
#define EPC (N_EDGES / CH)   // 12500 edges per chunk (c*EPC*4 B is 16B-aligned)
#define HALF 25000      // node half-range (packed 8-bit hist)
#define QTR 12500       // node quarter-range (cursors / float bins)
#define BSTRIDE 17      // uint4 per LDS row (odd -> conflict-free ds_read_b128)
#define AGG_NB (N_NODES / 4)   // 12500 agg blocks (4 waves, 1 row/wave)
#define GB ((N_NODES + 63) / 64)  // 782 gemm blocks

typedef __bf16 bf16x8 __attribute__((ext_vector_type(8)));
typedef float  f32x4  __attribute__((ext_vector_type(4)));
typedef float  f32x2  __attribute__((ext_vector_type(2)));

__device__ inline unsigned short f2bf(float f) {  // RNE fp32 -> bf16 bits
    unsigned u = __float_as_uint(f);
    u += 0x7FFF + ((u >> 16) & 1);
    return (unsigned short)(u >> 16);
}
__device__ inline unsigned packbf2(float a, float b) {
    return (unsigned)f2bf(a) | ((unsigned)f2bf(b) << 16);
}

// ---- fp8 e4m3 (OCP on gfx950) helpers ----
__device__ inline void fp8x8_to_f32(uint2 u, float* f) {
    f32x2 v0 = __builtin_amdgcn_cvt_pk_f32_fp8(u.x, false);
    f32x2 v1 = __builtin_amdgcn_cvt_pk_f32_fp8(u.x, true);
    f32x2 v2 = __builtin_amdgcn_cvt_pk_f32_fp8(u.y, false);
    f32x2 v3 = __builtin_amdgcn_cvt_pk_f32_fp8(u.y, true);
    f[0] = v0.x; f[1] = v0.y; f[2] = v1.x; f[3] = v1.y;
    f[4] = v2.x; f[5] = v2.y; f[6] = v3.x; f[7] = v3.y;
}
__device__ inline unsigned f32x4_to_fp8(float a, float b, float c, float d) {
    unsigned r = __builtin_amdgcn_cvt_pk_fp8_f32(a, b, 0, false);
    r = __builtin_amdgcn_cvt_pk_fp8_f32(c, d, r, true);
    return r;
}

// ---- 8-bit chunked histograms: block = (chunk, type, half) ----
// int4-vectorized edge loads. dst-blocks additionally emit per-1024-node-
// range partial degree sums (bsump[(c*2+h)][r]) — race-free.
__global__ __launch_bounds__(1024) void hist_kernel(const int* __restrict__ src,
                                                    const int* __restrict__ dst,
                                                    unsigned char* __restrict__ Hs8,
                                                    unsigned char* __restrict__ Hd8,
                                                    int* __restrict__ bsump) {
    __shared__ unsigned hist[HALF / 4];  // 25 KB (4x8-bit packed)
    int bx = blockIdx.x;                 // 256 blocks
    int c = bx >> 2, t = bx & 1, h = (bx >> 1) & 1;
    const int* ids = t ? dst : src;
    unsigned char* H = t ? Hd8 : Hs8;
    int base = h * HALF;
    for (int j = threadIdx.x; j < HALF / 4; j += 1024) hist[j] = 0;
    __syncthreads();
    const int4* ids4 = (const int4*)(ids + c * EPC);   // 16B-aligned
    for (int i = threadIdx.x; i < EPC / 4; i += 1024) {
        int4 v = ids4[i];
#pragma unroll
        for (int k = 0; k < 4; k++) {
            int id = ((k == 0) ? v.x : (k == 1) ? v.y : (k == 2) ? v.z : v.w) - base;
            if ((unsigned)id < (unsigned)HALF)
                atomicAdd(&hist[id >> 2], 1u << ((id & 3) * 8));
        }
    }
    __syncthreads();
    unsigned* Hw = (unsigned*)(H + (size_t)c * N_NODES + base);
    for (int j = threadIdx.x; j < HALF / 4; j += 1024) Hw[j] = hist[j];
    if (t) {  // per-range degD partials for the scan base
        int w = threadIdx.x >> 6, lane = threadIdx.x & 63;
        for (int r = w; r < SCAN_NB; r += 16) {
            int gi0 = max(r * 1024, base);
            int gi1 = min(r * 1024 + 1024, base + HALF);
            int s = 0;
            for (int li = gi0 - base + lane; li < gi1 - base; li += 64)
                s += (hist[li >> 2] >> ((li & 3) * 8)) & 255;
#pragma unroll
            for (int off = 32; off; off >>= 1) s += __shfl_down(s, off);
            if (lane == 0) bsump[(c * 2 + h) * SCAN_NB + r] = s;
        }
    }
}

// ---- scanC: degrees + norms + rowst + P8 in ONE chunk loop (49 x 1024) ----
__global__ __launch_bounds__(1024) void scanC_kernel(const unsigned char* __restrict__ Hs8,
                                                     const unsigned char* __restrict__ Hd8,
                                                     const int* __restrict__ bsump,
                                                     float* __restrict__ onorm,
                                                     float* __restrict__ inorm,
                                                     int* __restrict__ rowst,
                                                     unsigned char* __restrict__ P8) {
    __shared__ int wsum[16];
    __shared__ int tot[SCAN_NB];
    int t = threadIdx.x, lane = t & 63, w = t >> 6;
    int i = blockIdx.x * 1024 + t;
    if (t < SCAN_NB) {  // per-range degD totals (128 partials each)
        int s = 0;
        for (int p = 0; p < 2 * CH; p++) s += bsump[p * SCAN_NB + t];
        tot[t] = s;
    }
    int dd = 0;
    if (i < N_NODES) {
        int ds = 0, run = 0;
        for (int c = 0; c < CH; c++) {
            size_t o = (size_t)c * N_NODES + i;
            ds += Hs8[o];
            P8[o] = (unsigned char)run;   // within-row prefix (<= deg <= 255)
            run += Hd8[o];
        }
        dd = run;
        onorm[i] = rsqrtf(fmaxf((float)ds, 1.0f));
        inorm[i] = rsqrtf(fmaxf((float)dd, 1.0f));
    }
    int v = dd, incl = v;
#pragma unroll
    for (int off = 1; off < 64; off <<= 1) {
        int u = __shfl_up(incl, off);
        if (lane >= off) incl += u;
    }
    if (lane == 63) wsum[w] = incl;
    __syncthreads();
    if (t == 0) {
        int s = 0;
        for (int r = 0; r < (int)blockIdx.x; r++) s += tot[r];
#pragma unroll
        for (int k = 0; k < 16; k++) { int x = wsum[k]; wsum[k] = s; s += x; }
    }
    __syncthreads();
    incl += wsum[w];
    if (i < N_NODES) {
        rowst[i] = incl - v;           // exclusive prefix
        if (i == N_NODES - 1) rowst[N_NODES] = incl;
    }
}

// ---- tqsc: single-sweep tq-bin + scatter + prep tail: block = (chunk, q) ----
// ONE int4-vectorized pass over the chunk's edges; BOTH LDS images live:
//   src in quarter q -> float-bin atomicAdd (a[], 50KB) -> Tq
//   dst in quarter q -> cursor scatter (cur[], 50KB) -> esrc
__global__ __launch_bounds__(1024) void tqsc_kernel(const int* __restrict__ src,
                                                    const int* __restrict__ dst,
                                                    const float* __restrict__ inorm,
                                                    float* __restrict__ Tq,
                                                    const int* __restrict__ rowst,
                                                    const unsigned char* __restrict__ P8,
                                                    int* __restrict__ esrc,
                                                    const float* __restrict__ feat,
                                                    const float* __restrict__ onorm,
                                                    uint2* __restrict__ xq,
                                                    const float* __restrict__ W1,
                                                    const float* __restrict__ W2,
                                                    unsigned short* __restrict__ Wt) {
    __shared__ float a[QTR];   // 50 KB: t[s] bins (src-quarter)
    __shared__ int cur[QTR];   // 50 KB: scatter cursors (dst-quarter)
    int bx = blockIdx.x;       // 256 blocks
    int c = bx >> 2, q = bx & 3;
    int base = q * QTR;

    for (int j = threadIdx.x; j < QTR; j += 1024) {
        a[j] = 0.0f;
        cur[j] = rowst[base + j] + (int)P8[(size_t)c * N_NODES + base + j];
    }
    __syncthreads();

    // ---- single int4 edge sweep: bin by src-quarter, scatter by dst-q ----
    const int4* src4 = (const int4*)(src + c * EPC);   // 16B-aligned
    const int4* dst4 = (const int4*)(dst + c * EPC);
    for (int i = threadIdx.x; i < EPC / 4; i += 1024) {
        int4 s4 = src4[i], d4 = dst4[i];
#pragma unroll
        for (int k = 0; k < 4; k++) {
            int s = (k == 0) ? s4.x : (k == 1) ? s4.y : (k == 2) ? s4.z : s4.w;
            int d = (k == 0) ? d4.x : (k == 1) ? d4.y : (k == 2) ? d4.z : d4.w;
            int sq = s - base;
            if ((unsigned)sq < (unsigned)QTR)
                atomicAdd(&a[sq], inorm[d]);       // LDS float atomic
            int dq = d - base;
            if ((unsigned)dq < (unsigned)QTR) {
                int pos = atomicAdd(&cur[dq], 1);  // LDS atomic only
                esrc[pos] = s;
            }
        }
    }
    __syncthreads();
    for (int j = threadIdx.x; j < QTR; j += 1024)
        Tq[(size_t)c * N_NODES + base + j] = a[j];

    // ---- fused prep tail (grid-stride over the full machine) ----
    int T = gridDim.x * 1024;
    int id0 = bx * 1024 + threadIdx.x;
    for (int i = id0; i < N_NODES * F / 8; i += T) {
        float w = onorm[i >> 4];   // 16 uint2 per 128-col row
        const float4* xv = (const float4*)feat;
        float4 v0 = xv[i * 2], v1 = xv[i * 2 + 1];
        uint2 o;
        o.x = f32x4_to_fp8(v0.x * w, v0.y * w, v0.z * w, v0.w * w);
        o.y = f32x4_to_fp8(v1.x * w, v1.y * w, v1.z * w, v1.w * w);
        xq[i] = o;
    }
    for (int i = id0; i < 2 * F * F; i += T) {
        int wi = i >> 14, rem = i & 16383;
        int n = rem >> 7, k = rem & 127;
        const float* W = wi ? W2 : W1;
        Wt[(size_t)wi * F * F + (size_t)n * F + k] = f2bf(W[k * F + n]);
    }
}

// ---- aggregation: 4 waves/block, 1 dst row/wave; 16 lanes/edge fp8 uint2 ----
// QT=1: tail computes qt[i] = sum_c Tq[c][i]
template <int QT>
__global__ __launch_bounds__(256) void agg_csr_kernel(const uint2* __restrict__ xq,
                                                      uint4* __restrict__ mb,
                                                      const int* __restrict__ rowst,
                                                      const int* __restrict__ esrc,
                                                      const float* __restrict__ inorm,
                                                      const float* __restrict__ Tq,
                                                      float* __restrict__ qt) {
    int w = threadIdx.x >> 6;
    int lane = threadIdx.x & 63;
    int g = lane >> 4, t = lane & 15;
    int row = blockIdx.x * 4 + w;
    int beg = __builtin_amdgcn_readfirstlane(rowst[row]);
    int end = __builtin_amdgcn_readfirstlane(rowst[row + 1]);
    float acc[8];
#pragma unroll
    for (int k = 0; k < 8; k++) acc[k] = 0.0f;

    for (int e = beg; e < end; e += 16) {   // clamped, 4 gathers in flight
        int ea = min(e + g,      end - 1);
        int eb = min(e + 4 + g,  end - 1);
        int ec = min(e + 8 + g,  end - 1);
        int ed = min(e + 12 + g, end - 1);
        int sa = esrc[ea], sb = esrc[eb], sc = esrc[ec], sd = esrc[ed];
        uint2 ua = xq[(size_t)sa * 16 + t];
        uint2 ub = xq[(size_t)sb * 16 + t];
        uint2 uc = xq[(size_t)sc * 16 + t];
        uint2 ud = xq[(size_t)sd * 16 + t];
        float wa = (e + g      < end) ? 1.0f : 0.0f;
        float wb = (e + 4 + g  < end) ? 1.0f : 0.0f;
        float wc = (e + 8 + g  < end) ? 1.0f : 0.0f;
        float wd = (e + 12 + g < end) ? 1.0f : 0.0f;
        float fa[8], fb[8], fc[8], fd[8];
        fp8x8_to_f32(ua, fa); fp8x8_to_f32(ub, fb);
        fp8x8_to_f32(uc, fc); fp8x8_to_f32(ud, fd);
#pragma unroll
        for (int k = 0; k < 8; k++)
            acc[k] += fa[k] * wa + fb[k] * wb + fc[k] * wc + fd[k] * wd;
    }
#pragma unroll
    for (int k = 0; k < 8; k++) {
        acc[k] += __shfl_xor(acc[k], 16, 64);
        acc[k] += __shfl_xor(acc[k], 32, 64);
    }
    if (g == 0) {
        float inw = inorm[row];
        uint4 o;
        o.x = packbf2(acc[0] * inw, acc[1] * inw);
        o.y = packbf2(acc[2] * inw, acc[3] * inw);
        o.z = packbf2(acc[4] * inw, acc[5] * inw);
        o.w = packbf2(acc[6] * inw, acc[7] * inw);
        mb[(size_t)row * 16 + t] = o;
    }
    if (QT) {  // qt[i] = sum_c Tq[c][i]
        int i = blockIdx.x * 256 + threadIdx.x;
        if (i < N_NODES) {
            float s = 0.0f;
            for (int c = 0; c < CH; c++) s += Tq[(size_t)c * N_NODES + i];
            qt[i] = s;
        }
    }
}

// ---- MFMA GEMM, single bf16 W staged in LDS (one phase, 64 MFMA) ----
// FINAL=0: Y8 = fp8(onorm[row] * relu(A@W+b))  (layer 1)
// FINAL=1: no Y8; part2[block][col] = sum_rows qt[row]*onorm[row]*relu(...)
template <int FINAL>
__global__ __launch_bounds__(256) void mfma_gemm_kernel(const unsigned short* __restrict__ A,
                                                        const unsigned short* __restrict__ Wt,
                                                        const float* __restrict__ bias,
                                                        const float* __restrict__ onorm,
                                                        unsigned char* __restrict__ Y8,
                                                        const float* __restrict__ qt,
                                                        float* __restrict__ part2) {
    __shared__ uint4 sB[F * BSTRIDE];   // 34816 B
    __shared__ float sPf[4][F];         // 2 KB (FINAL only)
    int tid = threadIdx.x;
    int w = tid >> 6;
    int lane = tid & 63;
    int quad = lane >> 4, r16 = lane & 15;
    int row0 = blockIdx.x * 64 + w * 16;

    // preload A-frags (global, clamped) so loads overlap staging
    int arow = min(row0 + r16, N_NODES - 1);
    const uint4* Arow = (const uint4*)(A + (size_t)arow * F);
    uint4 a[4];
#pragma unroll
    for (int kk = 0; kk < 4; kk++) a[kk] = Arow[kk * 4 + quad];

    const uint4* G = (const uint4*)Wt;
    for (int j = tid; j < F * 16; j += 256)
        sB[(j >> 4) * BSTRIDE + (j & 15)] = G[j];

    f32x4 acc[8];
#pragma unroll
    for (int t = 0; t < 8; t++) acc[t] = (f32x4){0.f, 0.f, 0.f, 0.f};
    __syncthreads();

#pragma unroll
    for (int kk = 0; kk < 4; kk++) {
        bf16x8 av = __builtin_bit_cast(bf16x8, a[kk]);
#pragma unroll
        for (int t = 0; t < 8; t++) {
            bf16x8 bv = __builtin_bit_cast(bf16x8,
                sB[(t * 16 + r16) * BSTRIDE + kk * 4 + quad]);
            acc[t] = __builtin_amdgcn_mfma_f32_16x16x32_bf16(av, bv, acc[t], 0, 0, 0);
        }
    }

    float rw[4];
#pragma unroll
    for (int reg = 0; reg < 4; reg++) {
        int row = row0 + quad * 4 + reg;
        rw[reg] = (row < N_NODES) ? (FINAL ? qt[row] * onorm[row] : onorm[row]) : 0.0f;
    }

    if (!FINAL) {
#pragma unroll
        for (int t = 0; t < 8; t++) {
            int col = t * 16 + r16;
            float bb = bias[col];
#pragma unroll
            for (int reg = 0; reg < 4; reg++) {
                int row = row0 + quad * 4 + reg;
                if (row < N_NODES) {
                    float v = fmaxf(acc[t][reg] + bb, 0.0f) * rw[reg];
                    unsigned p = __builtin_amdgcn_cvt_pk_fp8_f32(v, v, 0, false);
                    Y8[(size_t)row * F + col] = (unsigned char)(p & 0xFF);
                }
            }
        }
    } else {
#pragma unroll
        for (int t = 0; t < 8; t++) {
            int col = t * 16 + r16;
            float bb = bias[col];
            float p = 0.0f;
#pragma unroll
            for (int reg = 0; reg < 4; reg++)
                p += fmaxf(acc[t][reg] + bb, 0.0f) * rw[reg];
            p += __shfl_xor(p, 16, 64);      // reduce over quad
            p += __shfl_xor(p, 32, 64);
            if (quad == 0) sPf[w][col] = p;
        }
        __syncthreads();
        if (tid < F)
            part2[(size_t)blockIdx.x * F + tid] =
                sPf[0][tid] + sPf[1][tid] + sPf[2][tid] + sPf[3][tid];
    }
}

// ---- final: c = (1/N) * sum_b part2[b] (b < GB), out = c @ W3 + b3 ----
__global__ __launch_bounds__(1024) void final_kernel(const float* __restrict__ part2,
                                                     const float* __restrict__ W3,
                                                     const float* __restrict__ b3,
                                                     float* __restrict__ out) {
    __shared__ float sc[8][F];  // 4 KB
    int tid = threadIdx.x;
    int col = tid & 127, sl = tid >> 7;
    float acc = 0.0f;
    for (int b = sl; b < GB; b += 8) acc += part2[(size_t)b * F + col];
    sc[sl][col] = acc;
    __syncthreads();
    if (tid < F) {
        float s = 0.0f;
#pragma unroll
        for (int k = 0; k < 8; k++) s += sc[k][tid];
        sc[0][tid] = s * (1.0f / (float)N_NODES);
    }
    __syncthreads();
    if (tid < F) {
        float o = b3[tid];
        for (int k = 0; k < F; k++) o += sc[0][k] * W3[k * F + tid];
        out[tid] = o;
    }
}

extern "C" void kernel_launch(void* const* d_in, const int* in_sizes, int n_in,
                              void* d_out, int out_size, void* d_ws, size_t ws_size,
                              hipStream_t stream) {
    const float* feat = (const float*)d_in[0];
    const float* W1   = (const float*)d_in[1];
    const float* b1   = (const float*)d_in[2];
    const float* W2   = (const float*)d_in[3];
    const float* b2   = (const float*)d_in[4];
    const float* W3   = (const float*)d_in[5];
    const float* b3   = (const float*)d_in[6];
    const int*   src  = (const int*)d_in[7];
    const int*   dst  = (const int*)d_in[8];
    float* out = (float*)d_out;

    // workspace layout (~53 MB, 16B-aligned blocks first)
    char* ws = (char*)d_ws;
    size_t off = 0;
    uint4* mb    = (uint4*)(ws + off); off += (size_t)N_NODES * F * 2;       // 12.8 MB bf16
    float* Tq    = (float*)(ws + off); off += (size_t)CH * N_NODES * 4;      // 12.8 MB
    uint2* xq    = (uint2*)(ws + off); off += (size_t)N_NODES * F;           // 6.4 MB fp8
    uint2* hq    = (uint2*)(ws + off); off += (size_t)N_NODES * F;           // 6.4 MB fp8
    unsigned char* Hs8 = (unsigned char*)(ws + off); off += (size_t)CH * N_NODES;  // 3.2 MB
    unsigned char* Hd8 = (unsigned char*)(ws + off); off += (size_t)CH * N_NODES;  // 3.2 MB
    unsigned char* P8  = (unsigned char*)(ws + off); off += (size_t)CH * N_NODES;  // 3.2 MB
    int*   esrc  = (int*)  (ws + off); off += (size_t)N_EDGES * 4;           // 3.2 MB
    unsigned short* Wt = (unsigned short*)(ws + off); off += 2 * F * F * 2;  // 64 KB bf16
    float* part2 = (float*)(ws + off); off += (size_t)GB * F * 4;            // 400 KB
    float* onorm = (float*)(ws + off); off += N_NODES * 4;
    float* inorm = (float*)(ws + off); off += N_NODES * 4;
    float* qt    = (float*)(ws + off); off += N_NODES * 4;
    int*   rowst = (int*)  (ws + off); off += (N_NODES + 1) * 4;
    int*   bsump = (int*)  (ws + off); off += 2 * CH * SCAN_NB * 4;          // 25 KB

    // CSR build — zero global atomics, zero memsets
    hist_kernel<<<4 * CH, 1024, 0, stream>>>(src, dst, Hs8, Hd8, bsump);
    scanC_kernel<<<SCAN_NB, 1024, 0, stream>>>(Hs8, Hd8, bsump, onorm, inorm,
                                               rowst, P8);
    tqsc_kernel<<<4 * CH, 1024, 0, stream>>>(src, dst, inorm, Tq, rowst, P8,
                                             esrc, feat, onorm, xq, W1, W2, Wt);

    // layer 1: agg(xq) -> mb (bf16, + qt tail), gemm -> hq (fp8, onorm-prescaled)
    agg_csr_kernel<1><<<AGG_NB, 256, 0, stream>>>(xq, mb, rowst, esrc, inorm, Tq, qt);
    mfma_gemm_kernel<0><<<GB, 256, 0, stream>>>((const unsigned short*)mb, Wt, b1,
                                                onorm, (unsigned char*)hq, qt, part2);
    // layer 2: agg(hq) -> mb, gemm(+fused layer-3 column sum) -> part2
    agg_csr_kernel<0><<<AGG_NB, 256, 0, stream>>>(hq, mb, rowst, esrc, inorm, Tq, qt);
    mfma_gemm_kernel<1><<<GB, 256, 0, stream>>>((const unsigned short*)mb, Wt + F * F,
                                                b2, onorm, (unsigned char*)hq, qt, part2);
    // final: c = (1/N) sum_b part2[b]; out = c @ W3 + b3
    final_kernel<<<1, 1024, 0, stream>>>(part2, W3, b3, out);
}